// Round 2
// 508.985 us; speedup vs baseline: 1.1054x; 1.1054x over previous
//
#include <hip/hip_runtime.h>
#include <hip/hip_bf16.h>

// GroupGMM: B=8192, I=512, G=32, C=16, D=32; out = concat(pi[16], mu[512], softplus(sig)[512])
#define BATCH 8192
#define IDIM  512
#define GDIM  32
#define NOUT  1040
#define NPAD  1152     // 9 * 128 n-tiles
#define KW    16384    // G*I
#define BM    128
#define BN    128
#define KQ    128      // I-quarter resident in LDS per outer pass

typedef short bf16x8 __attribute__((ext_vector_type(8)));   // 8 bf16 (4 VGPRs)
typedef float floatx4 __attribute__((ext_vector_type(4)));  // MFMA acc

__device__ inline unsigned pk2(float a, float b) {
    union { __hip_bfloat162 h2; unsigned u; } cv;
    cv.h2 = __float22bfloat162_rn(float2{a, b});
    return cv.u;
}

// ---- cvt fp32 -> bf16, 8 elems/thread (xb and gb) ---------------------------------
__global__ void cvt_bf16(const float* __restrict__ s, unsigned short* __restrict__ d) {
    int t = blockIdx.x * 256 + threadIdx.x;
    const float4* sp = (const float4*)s + (size_t)t * 2;
    float4 a = sp[0], b = sp[1];
    uint4 p;
    p.x = pk2(a.x, a.y); p.y = pk2(a.z, a.w);
    p.z = pk2(b.x, b.y); p.w = pk2(b.z, b.w);
    *(uint4*)(d + (size_t)t * 8) = p;
}

// ---- prep: Bpack — per K=32-step 8 KB lane-ordered slabs --------------------------
// idx(n,k): col=n>>7, r=n&127 -> h=r>>6, tn=(r>>4)&3, l15=r&15; kk=k>>5, q=(k>>3)&3,
//           j=k&7 ->  (col*512+kk)*4096 + (((h*4+tn)*4+q)*16 + l15)*8 + j
__global__ void prep_wt(const float* __restrict__ Wmu, const float* __restrict__ Wsig,
                        const float* __restrict__ Wpi, unsigned short* __restrict__ Wt) {
    int n = blockIdx.y * 256 + threadIdx.x;
    if (n >= NPAD) return;
    int k0 = blockIdx.x * 8;
    float v[8];
#pragma unroll
    for (int j = 0; j < 8; ++j) {
        int k = k0 + j, gg = k >> 9, i = k & 511;
        float val = 0.0f;
        if (n < 16)         val = Wpi [(gg * 512 + i) * 16  + n];
        else if (n < 528)   val = Wmu [(gg * 512 + i) * 512 + (n - 16)];
        else if (n < NOUT)  val = Wsig[(gg * 512 + i) * 512 + (n - 528)];
        v[j] = val;
    }
    uint4 p;
    p.x = pk2(v[0], v[1]); p.y = pk2(v[2], v[3]);
    p.z = pk2(v[4], v[5]); p.w = pk2(v[6], v[7]);
    const int col = n >> 7, r = n & 127;
    const int h = r >> 6, tn = (r >> 4) & 3, l15 = r & 15;
    const int kk = k0 >> 5, q = (k0 >> 3) & 3;
    size_t idx = ((size_t)(col * 512 + kk) << 12) + ((((h * 4 + tn) * 4 + q) * 16 + l15) * 8);
    *(uint4*)&Wt[idx] = p;
}

// ---- prep: Wb[n][32] bf16 = concatenated biases, n-major --------------------------
__global__ void prep_wb(const float* __restrict__ bmu, const float* __restrict__ bsig,
                        const float* __restrict__ bpi, unsigned short* __restrict__ Wb) {
    int n = blockIdx.y * 256 + threadIdx.x;
    if (n >= NPAD) return;
    int k0 = blockIdx.x * 8;
    float v[8];
#pragma unroll
    for (int j = 0; j < 8; ++j) {
        int gg = k0 + j;
        float val = 0.0f;
        if (n < 16)         val = bpi [gg * 16  + n];
        else if (n < 528)   val = bmu [gg * 512 + (n - 16)];
        else if (n < NOUT)  val = bsig[gg * 512 + (n - 528)];
        v[j] = val;
    }
    uint4 p;
    p.x = pk2(v[0], v[1]); p.y = pk2(v[2], v[3]);
    p.z = pk2(v[4], v[5]); p.w = pk2(v[6], v[7]);
    *(uint4*)&Wb[(size_t)n * GDIM + k0] = p;
}

// ---- GEMM: A I-quarter LDS-resident, B streamed (packed, coalesced), XCD-pinned ---
// out[m,n] = sum_gg g[m,gg]*(xb[m,:] @ W_gg[:,n]) + gb[m,:] @ Wb[:,n]^T
// Running-rescale trick: acc is held in the "/ g[m,gg_cur]" domain. Before each group
// segment: acc *= g_prev/g_cur (ratio table in LDS); MFMA accumulates the raw group
// product directly (no separate P accumulator -> frees 64 VGPRs, halves fold VALU).
// After the last segment: acc *= g[m,31] returns to the final domain, then bias MFMA.
__global__ __launch_bounds__(256, 2) void gemm_gmm(
        const unsigned short* __restrict__ xb, const unsigned short* __restrict__ gb,
        const float* __restrict__ g, const unsigned short* __restrict__ Wt,
        const unsigned short* __restrict__ Wb, float* __restrict__ out) {
    __shared__ unsigned short lA[BM * KQ];     // 32 KB, XOR-swizzled 16B granules
    __shared__ float ratL[GDIM * BM];          // 16 KB f32: [gg][row] = g[gg-1]/g[gg]
    __shared__ float g31L[BM];                 // 0.5 KB f32: g[row][31] (final scale)

    const int t = threadIdx.x, lane = t & 63, w = t >> 6;
    const int wm = (w & 1) * 64, wn = (w >> 1) * 64;   // 2x2 waves of 64m x 64n
    const int q = lane >> 4, l15 = lane & 15;

    // XCD pinning (xcd = bx & 7 round-robin): each XCD walks mblk-major within
    // ~1.125 n-columns -> active Wt slabs stay in its 4 MB L2.
    const int bx = blockIdx.x;                  // 0..575
    const int seq = (bx & 7) * 72 + (bx >> 3);  // bijection 0..575
    const int col = seq >> 6, mblk = seq & 63;
    const int m0 = mblk * BM, n0 = col * BN;

    // ---- B base: per-step 8 KB slab; this wave's lane offset ----------------------
    const unsigned short* Bbase = Wt + ((size_t)col * 512 << 12)
                                + (((wn >> 6) * 256 + lane) * 8);

    floatx4 acc[4][4] = {};
    uint4 breg[4][4];                           // ring-4 B steps (64 VGPRs), depth-3 prefetch
    floatx4 r4[4];                              // pipelined ratio frags for current group
    const int swA = l15 & 7;

    // flat kk = ((kb*32+gg)<<2)+ks  ->  global step kg = gg*16 + kb*4 + ks
    auto loadB = [&](int kk, int slot) {
        const unsigned kg = (((kk >> 2) & 31) * 16) + ((kk >> 7) * 4) + (kk & 3);
        const unsigned short* p = Bbase + ((size_t)kg << 12);
#pragma unroll
        for (int tn = 0; tn < 4; ++tn)
            breg[slot][tn] = *(const uint4*)(p + tn * 512);  // imm offsets 0/1/2/3 KB
    };
    auto loadR = [&](int gg) {
#pragma unroll
        for (int tm = 0; tm < 4; ++tm)
            r4[tm] = *(const floatx4*)&ratL[gg * BM + wm + tm * 16 + q * 4];
    };

    loadB(0, 0); loadB(1, 1); loadB(2, 2);      // fill prefetch pipe early

    // ---- ratio table + final scale -> LDS, [gg][row] ------------------------------
#pragma unroll
    for (int j = 0; j < 16; ++j) {
        int idx = t + 256 * j;                  // idx = gg*128 + row
        int gg = idx >> 7, row = idx & 127;
        float cur  = g[(size_t)(m0 + row) * GDIM + gg];
        float prev = g[(size_t)(m0 + row) * GDIM + ((gg + 31) & 31)];
        ratL[idx] = prev / cur;                 // softmax output: cur > 0 always
    }
    if (t < BM) g31L[t] = g[(size_t)(m0 + t) * GDIM + 31];
    __syncthreads();
    loadR(0);                                   // pipeline head: ratios for (kb=0, gg=0)

    for (int kb = 0; kb < 4; ++kb) {
        __syncthreads();                        // prior kb's lA reads complete
        {   // stage A quarter: row = t>>1, granules gi = (t&1)*8 + j
            const int r = t >> 1;
            const unsigned short* src = xb + (size_t)(m0 + r) * IDIM + kb * KQ + (t & 1) * 64;
#pragma unroll
            for (int j = 0; j < 8; ++j) {
                int gi = (t & 1) * 8 + j;
                uint4 v = *(const uint4*)(src + j * 8);
                *(uint4*)&lA[(r * 16 + (gi ^ (r & 7))) * 8] = v;
            }
        }
        __syncthreads();

        for (int gg = 0; gg < GDIM; ++gg) {
            // rescale acc into group-gg domain (r4 preloaded during prior MFMAs)
#pragma unroll
            for (int tm = 0; tm < 4; ++tm)
#pragma unroll
                for (int tn = 0; tn < 4; ++tn)
#pragma unroll
                    for (int r = 0; r < 4; ++r)
                        acc[tm][tn][r] *= r4[tm][r];
            loadR((gg + 1) & 31);               // prefetch next group's ratios

#pragma unroll
            for (int ks = 0; ks < 4; ++ks) {
                const int kk = ((kb * GDIM + gg) << 2) + ks;
                if (kk + 3 < 512) loadB(kk + 3, (ks + 3) & 3);  // depth-3 prefetch
                bf16x8 af[4];
#pragma unroll
                for (int tm = 0; tm < 4; ++tm)
                    af[tm] = *(const bf16x8*)
                        &lA[((wm + tm * 16 + l15) * 16 + ((ks * 4 + q) ^ swA)) * 8];
#pragma unroll
                for (int tm = 0; tm < 4; ++tm)
#pragma unroll
                    for (int tn = 0; tn < 4; ++tn)
                        acc[tm][tn] = __builtin_amdgcn_mfma_f32_16x16x32_bf16(
                            af[tm], *(const bf16x8*)&breg[ks][tn], acc[tm][tn], 0, 0, 0);
            }
        }
    }

    // ---- back to final domain: acc *= g[m,31] -------------------------------------
#pragma unroll
    for (int tm = 0; tm < 4; ++tm) {
        floatx4 gl = *(const floatx4*)&g31L[wm + tm * 16 + q * 4];
#pragma unroll
        for (int tn = 0; tn < 4; ++tn)
#pragma unroll
            for (int r = 0; r < 4; ++r)
                acc[tm][tn][r] *= gl[r];
    }

    // ---- bias: stage gb tile into lA (stride 40), one K=32 MFMA per frag ---------
    __syncthreads();
    {
        const int r = t >> 1;
        const unsigned short* src = gb + (size_t)(m0 + r) * GDIM + (t & 1) * 16;
        *(uint4*)&lA[r * 40 + (t & 1) * 16]     = *(const uint4*)(src);
        *(uint4*)&lA[r * 40 + (t & 1) * 16 + 8] = *(const uint4*)(src + 8);
    }
    __syncthreads();
    {
        bf16x8 afb[4], bb[4];
#pragma unroll
        for (int tm = 0; tm < 4; ++tm)
            afb[tm] = *(const bf16x8*)&lA[(wm + tm * 16 + l15) * 40 + q * 8];
#pragma unroll
        for (int tn = 0; tn < 4; ++tn)
            bb[tn] = *(const bf16x8*)(Wb + (size_t)(n0 + wn + tn * 16 + l15) * GDIM + q * 8);
#pragma unroll
        for (int tm = 0; tm < 4; ++tm)
#pragma unroll
            for (int tn = 0; tn < 4; ++tn)
                acc[tm][tn] = __builtin_amdgcn_mfma_f32_16x16x32_bf16(
                    afb[tm], bb[tn], acc[tm][tn], 0, 0, 0);
    }

    // ---- epilogue: fused softplus on sigma region, direct store ------------------
#pragma unroll
    for (int tn = 0; tn < 4; ++tn) {
        int n = n0 + wn + tn * 16 + l15;
        if (n >= NOUT) continue;
        bool is_scale = (n >= 528);
#pragma unroll
        for (int tm = 0; tm < 4; ++tm) {
            int mbase = m0 + wm + tm * 16 + q * 4;
#pragma unroll
            for (int r = 0; r < 4; ++r) {
                float vv = acc[tm][tn][r];
                if (is_scale) {
                    float sp = (vv > 15.0f) ? vv : log1pf(expf(vv));
                    vv = sp + 1e-7f;
                }
                out[(size_t)(mbase + r) * NOUT + n] = vv;
            }
        }
    }
}

extern "C" void kernel_launch(void* const* d_in, const int* in_sizes, int n_in,
                              void* d_out, int out_size, void* d_ws, size_t ws_size,
                              hipStream_t stream) {
    const float* x    = (const float*)d_in[0];
    const float* g    = (const float*)d_in[1];
    const float* Wmu  = (const float*)d_in[2];
    const float* bmu  = (const float*)d_in[3];
    const float* Wsig = (const float*)d_in[4];
    const float* bsig = (const float*)d_in[5];
    const float* Wpi  = (const float*)d_in[6];
    const float* bpi  = (const float*)d_in[7];
    float* out = (float*)d_out;

    // workspace (~46.3 MB)
    char* ws = (char*)d_ws;
    unsigned short* Wt = (unsigned short*)ws;  ws += (size_t)NPAD * KW * 2;     // 37.75 MB
    unsigned short* xb = (unsigned short*)ws;  ws += (size_t)BATCH * IDIM * 2;  //  8.0 MB
    unsigned short* gb = (unsigned short*)ws;  ws += (size_t)BATCH * GDIM * 2;  //  0.5 MB
    unsigned short* Wb = (unsigned short*)ws;                                   //  0.07 MB

    cvt_bf16<<<BATCH * IDIM / 2048, 256, 0, stream>>>(x, xb);
    cvt_bf16<<<BATCH * GDIM / 2048, 256, 0, stream>>>(g, gb);
    prep_wt<<<dim3(KW / 8, 5), 256, 0, stream>>>(Wmu, Wsig, Wpi, Wt);
    prep_wb<<<dim3(GDIM / 8, 5), 256, 0, stream>>>(bmu, bsig, bpi, Wb);
    gemm_gmm<<<(BATCH / BM) * (NPAD / BN), 256, 0, stream>>>(xb, gb, g, Wt, Wb, out);
}

// Round 5
// 493.026 us; speedup vs baseline: 1.1412x; 1.0324x over previous
//
#include <hip/hip_runtime.h>
#include <hip/hip_bf16.h>

// GroupGMM: B=8192, I=512, G=32, C=16, D=32; out = concat(pi[16], mu[512], softplus(sig)[512])
#define BATCH 8192
#define IDIM  512
#define GDIM  32
#define NOUT  1040
#define NPAD  1152     // 9 * 128 n-tiles
#define KW    16384    // G*I
#define BM    128
#define BN    128
#define KQ    128      // I-quarter resident in LDS per outer pass

typedef short bf16x8 __attribute__((ext_vector_type(8)));   // 8 bf16 (4 VGPRs)
typedef float floatx4 __attribute__((ext_vector_type(4)));  // MFMA acc

__device__ inline unsigned pk2(float a, float b) {
    union { __hip_bfloat162 h2; unsigned u; } cv;
    cv.h2 = __float22bfloat162_rn(float2{a, b});
    return cv.u;
}

// ---- cvt fp32 -> bf16, 8 elems/thread (xb and gb) ---------------------------------
__global__ void cvt_bf16(const float* __restrict__ s, unsigned short* __restrict__ d) {
    int t = blockIdx.x * 256 + threadIdx.x;
    const float4* sp = (const float4*)s + (size_t)t * 2;
    float4 a = sp[0], b = sp[1];
    uint4 p;
    p.x = pk2(a.x, a.y); p.y = pk2(a.z, a.w);
    p.z = pk2(b.x, b.y); p.w = pk2(b.z, b.w);
    *(uint4*)(d + (size_t)t * 8) = p;
}

// ---- prep: Bpack — per K=32-step 8 KB lane-ordered slabs --------------------------
// idx(n,k): col=n>>7, r=n&127 -> h=r>>6, tn=(r>>4)&3, l15=r&15; kk=k>>5, q=(k>>3)&3,
//           j=k&7 ->  (col*512+kk)*4096 + (((h*4+tn)*4+q)*16 + l15)*8 + j
__global__ void prep_wt(const float* __restrict__ Wmu, const float* __restrict__ Wsig,
                        const float* __restrict__ Wpi, unsigned short* __restrict__ Wt) {
    int n = blockIdx.y * 256 + threadIdx.x;
    if (n >= NPAD) return;
    int k0 = blockIdx.x * 8;
    float v[8];
#pragma unroll
    for (int j = 0; j < 8; ++j) {
        int k = k0 + j, gg = k >> 9, i = k & 511;
        float val = 0.0f;
        if (n < 16)         val = Wpi [(gg * 512 + i) * 16  + n];
        else if (n < 528)   val = Wmu [(gg * 512 + i) * 512 + (n - 16)];
        else if (n < NOUT)  val = Wsig[(gg * 512 + i) * 512 + (n - 528)];
        v[j] = val;
    }
    uint4 p;
    p.x = pk2(v[0], v[1]); p.y = pk2(v[2], v[3]);
    p.z = pk2(v[4], v[5]); p.w = pk2(v[6], v[7]);
    const int col = n >> 7, r = n & 127;
    const int h = r >> 6, tn = (r >> 4) & 3, l15 = r & 15;
    const int kk = k0 >> 5, q = (k0 >> 3) & 3;
    size_t idx = ((size_t)(col * 512 + kk) << 12) + ((((h * 4 + tn) * 4 + q) * 16 + l15) * 8);
    *(uint4*)&Wt[idx] = p;
}

// ---- prep: Wb[n][32] bf16 = concatenated biases, n-major --------------------------
__global__ void prep_wb(const float* __restrict__ bmu, const float* __restrict__ bsig,
                        const float* __restrict__ bpi, unsigned short* __restrict__ Wb) {
    int n = blockIdx.y * 256 + threadIdx.x;
    if (n >= NPAD) return;
    int k0 = blockIdx.x * 8;
    float v[8];
#pragma unroll
    for (int j = 0; j < 8; ++j) {
        int gg = k0 + j;
        float val = 0.0f;
        if (n < 16)         val = bpi [gg * 16  + n];
        else if (n < 528)   val = bmu [gg * 512 + (n - 16)];
        else if (n < NOUT)  val = bsig[gg * 512 + (n - 528)];
        v[j] = val;
    }
    uint4 p;
    p.x = pk2(v[0], v[1]); p.y = pk2(v[2], v[3]);
    p.z = pk2(v[4], v[5]); p.w = pk2(v[6], v[7]);
    *(uint4*)&Wb[(size_t)n * GDIM + k0] = p;
}

// ---- GEMM: A I-quarter LDS-resident, B streamed (packed, coalesced), XCD-pinned ---
// out[m,n] = sum_gg g[m,gg]*(xb[m,:] @ W_gg[:,n]) + gb[m,:] @ Wb[:,n]^T
// Running-rescale: acc held in "/ g[m,gg_cur]" domain; per-group ratio mul, final *g31.
// A fragments hoisted to registers ONCE PER KB (identical across all 32 groups) ->
// 32x fewer LDS reads, no in-loop ds_read->MFMA dependency. Tile-major inner loop:
// per (tm,tn): 4-mul rescale + 4 dependent MFMAs (16 independent chains); breg column
// tn refilled for group+1 right after its last use (counted-vmcnt prefetch, ~1 round).
__global__ __launch_bounds__(256, 2) void gemm_gmm(
        const unsigned short* __restrict__ xb, const unsigned short* __restrict__ gb,
        const float* __restrict__ g, const unsigned short* __restrict__ Wt,
        const unsigned short* __restrict__ Wb, float* __restrict__ out) {
    __shared__ unsigned short lA[BM * KQ];     // 32 KB, XOR-swizzled 16B granules
    __shared__ float ratL[GDIM * BM];          // 16 KB f32: [gg][row] = g[gg-1]/g[gg]
    __shared__ float g31L[BM];                 // 0.5 KB f32: g[row][31] (final scale)

    const int t = threadIdx.x, lane = t & 63, w = t >> 6;
    const int wm = (w & 1) * 64, wn = (w >> 1) * 64;   // 2x2 waves of 64m x 64n
    const int q = lane >> 4, l15 = lane & 15;

    // XCD pinning (xcd = bx & 7 round-robin): each XCD walks mblk-major within
    // ~1.125 n-columns -> active Wt slabs stay in its 4 MB L2.
    const int bx = blockIdx.x;                  // 0..575
    const int seq = (bx & 7) * 72 + (bx >> 3);  // bijection 0..575
    const int col = seq >> 6, mblk = seq & 63;
    const int m0 = mblk * BM, n0 = col * BN;

    // ---- B base: per-step 8 KB slab; this wave's lane offset ----------------------
    const unsigned short* Bbase = Wt + ((size_t)col * 512 << 12)
                                + (((wn >> 6) * 256 + lane) * 8);

    floatx4 acc[4][4] = {};
    uint4 breg[4][4];                           // current group's B steps (64 VGPRs)
    bf16x8 af[4][4];                            // [ks][tm] A frags, hoisted per kb (64 VGPRs)
    floatx4 r4[4];                              // current group's rescale ratios
    const int swA = l15 & 7;

    // column tn of group 'flat' (flat = kb*32+gg): 4 ks steps, 8 KB apart
    auto loadBcol = [&](int flat, int tn) {
        const int ggv = flat & 31, kbv = flat >> 5;
        const unsigned short* p = Bbase + ((size_t)(ggv * 16 + kbv * 4) << 12) + tn * 512;
#pragma unroll
        for (int ks = 0; ks < 4; ++ks)
            breg[ks][tn] = *(const uint4*)(p + (ks << 12));
    };
    auto loadR = [&](int gg) {
#pragma unroll
        for (int tm = 0; tm < 4; ++tm)
            r4[tm] = *(const floatx4*)&ratL[gg * BM + wm + tm * 16 + q * 4];
    };

#pragma unroll
    for (int tn = 0; tn < 4; ++tn) loadBcol(0, tn);   // fill pipe for (kb=0, gg=0)

    // ---- ratio table + final scale -> LDS, [gg][row] ------------------------------
#pragma unroll
    for (int j = 0; j < 16; ++j) {
        int idx = t + 256 * j;                  // idx = gg*128 + row
        int gg = idx >> 7, row = idx & 127;
        float cur  = g[(size_t)(m0 + row) * GDIM + gg];
        float prev = g[(size_t)(m0 + row) * GDIM + ((gg + 31) & 31)];
        ratL[idx] = prev / cur;                 // softmax output: cur > 0 always
    }
    if (t < BM) g31L[t] = g[(size_t)(m0 + t) * GDIM + 31];
    __syncthreads();
    loadR(0);

    for (int kb = 0; kb < 4; ++kb) {
        __syncthreads();                        // prior kb's lA reads complete
        {   // stage A quarter: row = t>>1, granules gi = (t&1)*8 + j
            const int r = t >> 1;
            const unsigned short* src = xb + (size_t)(m0 + r) * IDIM + kb * KQ + (t & 1) * 64;
#pragma unroll
            for (int j = 0; j < 8; ++j) {
                int gi = (t & 1) * 8 + j;
                uint4 v = *(const uint4*)(src + j * 8);
                *(uint4*)&lA[(r * 16 + (gi ^ (r & 7))) * 8] = v;
            }
        }
        __syncthreads();

        // hoist this kb's A fragments into registers (reused by all 32 groups)
#pragma unroll
        for (int ks = 0; ks < 4; ++ks)
#pragma unroll
            for (int tm = 0; tm < 4; ++tm)
                af[ks][tm] = *(const bf16x8*)
                    &lA[((wm + tm * 16 + l15) * 16 + ((ks * 4 + q) ^ swA)) * 8];

        for (int gg = 0; gg < GDIM; ++gg) {
            const int flat = kb * GDIM + gg;
#pragma unroll
            for (int tn = 0; tn < 4; ++tn) {
#pragma unroll
                for (int tm = 0; tm < 4; ++tm) {
                    // rescale this tile into group-gg domain, then its 4 MFMAs
#pragma unroll
                    for (int r = 0; r < 4; ++r)
                        acc[tm][tn][r] *= r4[tm][r];
#pragma unroll
                    for (int ks = 0; ks < 4; ++ks)
                        acc[tm][tn] = __builtin_amdgcn_mfma_f32_16x16x32_bf16(
                            af[ks][tm], *(const bf16x8*)&breg[ks][tn], acc[tm][tn], 0, 0, 0);
                }
                // breg[*][tn] dead for this group: refill with next group's column
                if (flat + 1 < 128) loadBcol(flat + 1, tn);
            }
            loadR((gg + 1) & 31);   // WAR lets compiler lift to just after last r4 read
        }
    }

    // ---- back to final domain: acc *= g[m,31] -------------------------------------
#pragma unroll
    for (int tm = 0; tm < 4; ++tm) {
        floatx4 gl = *(const floatx4*)&g31L[wm + tm * 16 + q * 4];
#pragma unroll
        for (int tn = 0; tn < 4; ++tn)
#pragma unroll
            for (int r = 0; r < 4; ++r)
                acc[tm][tn][r] *= gl[r];
    }

    // ---- bias: stage gb tile into lA (stride 40), one K=32 MFMA per frag ---------
    __syncthreads();
    {
        const int r = t >> 1;
        const unsigned short* src = gb + (size_t)(m0 + r) * GDIM + (t & 1) * 16;
        *(uint4*)&lA[r * 40 + (t & 1) * 16]     = *(const uint4*)(src);
        *(uint4*)&lA[r * 40 + (t & 1) * 16 + 8] = *(const uint4*)(src + 8);
    }
    __syncthreads();
    {
        bf16x8 afb[4], bb[4];
#pragma unroll
        for (int tm = 0; tm < 4; ++tm)
            afb[tm] = *(const bf16x8*)&lA[(wm + tm * 16 + l15) * 40 + q * 8];
#pragma unroll
        for (int tn = 0; tn < 4; ++tn)
            bb[tn] = *(const bf16x8*)(Wb + (size_t)(n0 + wn + tn * 16 + l15) * GDIM + q * 8);
#pragma unroll
        for (int tm = 0; tm < 4; ++tm)
#pragma unroll
            for (int tn = 0; tn < 4; ++tn)
                acc[tm][tn] = __builtin_amdgcn_mfma_f32_16x16x32_bf16(
                    afb[tm], bb[tn], acc[tm][tn], 0, 0, 0);
    }

    // ---- epilogue: fused softplus on sigma region, direct store ------------------
#pragma unroll
    for (int tn = 0; tn < 4; ++tn) {
        int n = n0 + wn + tn * 16 + l15;
        if (n >= NOUT) continue;
        bool is_scale = (n >= 528);
#pragma unroll
        for (int tm = 0; tm < 4; ++tm) {
            int mbase = m0 + wm + tm * 16 + q * 4;
#pragma unroll
            for (int r = 0; r < 4; ++r) {
                float vv = acc[tm][tn][r];
                if (is_scale) {
                    float sp = (vv > 15.0f) ? vv : log1pf(expf(vv));
                    vv = sp + 1e-7f;
                }
                out[(size_t)(mbase + r) * NOUT + n] = vv;
            }
        }
    }
}

extern "C" void kernel_launch(void* const* d_in, const int* in_sizes, int n_in,
                              void* d_out, int out_size, void* d_ws, size_t ws_size,
                              hipStream_t stream) {
    const float* x    = (const float*)d_in[0];
    const float* g    = (const float*)d_in[1];
    const float* Wmu  = (const float*)d_in[2];
    const float* bmu  = (const float*)d_in[3];
    const float* Wsig = (const float*)d_in[4];
    const float* bsig = (const float*)d_in[5];
    const float* Wpi  = (const float*)d_in[6];
    const float* bpi  = (const float*)d_in[7];
    float* out = (float*)d_out;

    // workspace (~46.3 MB)
    char* ws = (char*)d_ws;
    unsigned short* Wt = (unsigned short*)ws;  ws += (size_t)NPAD * KW * 2;     // 37.75 MB
    unsigned short* xb = (unsigned short*)ws;  ws += (size_t)BATCH * IDIM * 2;  //  8.0 MB
    unsigned short* gb = (unsigned short*)ws;  ws += (size_t)BATCH * GDIM * 2;  //  0.5 MB
    unsigned short* Wb = (unsigned short*)ws;                                   //  0.07 MB

    cvt_bf16<<<BATCH * IDIM / 2048, 256, 0, stream>>>(x, xb);
    cvt_bf16<<<BATCH * GDIM / 2048, 256, 0, stream>>>(g, gb);
    prep_wt<<<dim3(KW / 8, 5), 256, 0, stream>>>(Wmu, Wsig, Wpi, Wt);
    prep_wb<<<dim3(GDIM / 8, 5), 256, 0, stream>>>(bmu, bsig, bpi, Wb);
    gemm_gmm<<<(BATCH / BM) * (NPAD / BN), 256, 0, stream>>>(xb, gb, g, Wt, Wb, out);
}